// Round 5
// baseline (1002.147 us; speedup 1.0000x reference)
//
#include <hip/hip_runtime.h>

// ---------------------------------------------------------------------------
// Swin shifted-window attention, fully fused: one block = one 8x8 window.
// B=16 H=W=128 C=256 NH=8 HD=32 N=64 tokens, shift 4, 4096 windows.
// bf16 MFMA (16x16x32) compute, fp32 accumulate, fp32 in/out.
// ---------------------------------------------------------------------------

typedef float f32x4 __attribute__((ext_vector_type(4)));
typedef __bf16 bf16x8 __attribute__((ext_vector_type(8)));
typedef unsigned short u16x4 __attribute__((ext_vector_type(4)));
typedef unsigned short u16x8 __attribute__((ext_vector_type(8)));

#define MFMA16(a, b, c) __builtin_amdgcn_mfma_f32_16x16x32_bf16((a), (b), (c), 0, 0, 0)

__device__ __forceinline__ unsigned short f2bf(float f) {
  union { float f; unsigned u; } v; v.f = f;
  unsigned r = v.u + 0x7FFFu + ((v.u >> 16) & 1u);   // RNE
  return (unsigned short)(r >> 16);
}

__device__ __forceinline__ bf16x8 pack8(float4 f0, float4 f1) {
  union { u16x8 s; bf16x8 v; } u;
  u.s[0] = f2bf(f0.x); u.s[1] = f2bf(f0.y); u.s[2] = f2bf(f0.z); u.s[3] = f2bf(f0.w);
  u.s[4] = f2bf(f1.x); u.s[5] = f2bf(f1.y); u.s[6] = f2bf(f1.z); u.s[7] = f2bf(f1.w);
  return u.v;
}

// 8-ushort load that only needs 8-byte alignment (stride-36 rows)
__device__ __forceinline__ bf16x8 ld8u(const unsigned short* p) {
  union { unsigned long long q[2]; bf16x8 v; } u;
  u.q[0] = *(const unsigned long long*)(p);
  u.q[1] = *(const unsigned long long*)(p + 4);
  return u.v;
}

// LDS layout in ushort units. Total 77344 ushorts = 154,688 B (<= 160 KiB).
// q  : [8][64][36]  (token-major, stride 36 to dodge bank conflicts)
// k  : [8][64][36]
// v_t: [8][32][72]  (dim-major / transposed, stride 72 = 16B-aligned rows)
// tab: 1800 f32 rel-bias table
// P/x: overlay region: x window [64][256] bf16 (QKV phase) then 4x per-wave
//      P scratch [64][72] bf16 (attention phase)
#define Q_OFF   0
#define K_OFF   18432
#define V_OFF   36864
#define TAB_OFF 55296
#define P_OFF   58912
#define SM_TOT  77344

__global__ void conv_weights(const float* __restrict__ qkvW, const float* __restrict__ projW,
                             unsigned short* __restrict__ wq, unsigned short* __restrict__ wp) {
  int i = blockIdx.x * 256 + threadIdx.x;
  if (i < 196608) wq[i] = f2bf(qkvW[i]);
  if (i < 65536)  wp[i] = f2bf(projW[i]);
}

template <bool PRE>
__global__ __launch_bounds__(256, 1) void swin_fused(
    const float* __restrict__ x,
    const float* __restrict__ qkvWf,
    const float* __restrict__ qkvB,
    const float* __restrict__ projWf,
    const float* __restrict__ projB,
    const float* __restrict__ relTab,
    const unsigned short* __restrict__ qkvWb,
    const unsigned short* __restrict__ projWb,
    float* __restrict__ out) {
  __shared__ unsigned short sm[SM_TOT];
  const f32x4 Z = {0.0f, 0.0f, 0.0f, 0.0f};

  const int tid = threadIdx.x;
  const int wv  = tid >> 6;          // wave 0..3
  const int lane = tid & 63;
  const int g  = lane >> 4;          // 16-lane group 0..3
  const int cl = lane & 15;
  const int blk = blockIdx.x;
  const int b  = blk >> 8;           // batch
  const int w  = blk & 255;          // window id
  const int wi = w >> 4, wj = w & 15;
  const bool er = (wi == 15), ec = (wj == 15);   // edge windows carry the shift mask

  // ---- stage rel-bias table (1800 f32) ----
  {
    float* t = (float*)(sm + TAB_OFF);
    for (int i = tid; i < 1800; i += 256) t[i] = relTab[i];
  }
  // ---- stage x window: shift-gather, fp32->bf16, chunk-XOR swizzle ----
  {
    unsigned short* X = sm + P_OFF;
    const float* xb = x + (size_t)b * (128 * 128 * 256);
#pragma unroll
    for (int it = 0; it < 8; ++it) {
      int idx = tid + it * 256;            // 64 tokens x 32 chunks of 8
      int t = idx >> 5, ch = idx & 31;
      int hh = (wi * 8 + (t >> 3) + 4) & 127;   // roll(-4) gather
      int ww = (wj * 8 + (t & 7) + 4) & 127;
      const float* src = xb + (((hh << 7) + ww) << 8) + ch * 8;
      float4 f0 = *(const float4*)src;
      float4 f1 = *(const float4*)(src + 4);
      u16x8 pk;
      pk[0] = f2bf(f0.x); pk[1] = f2bf(f0.y); pk[2] = f2bf(f0.z); pk[3] = f2bf(f0.w);
      pk[4] = f2bf(f1.x); pk[5] = f2bf(f1.y); pk[6] = f2bf(f1.z); pk[7] = f2bf(f1.w);
      *(u16x8*)(X + t * 256 + ((ch ^ (t & 7)) << 3)) = pk;   // swizzled chunk
    }
  }
  __syncthreads();

  // ---- QKV GEMM: [64 x 256] @ W^T -> [64 x 768], epilogue scatters to q/k/v_t ----
  {
    const unsigned short* X = sm + P_OFF;
    for (int ct = wv * 12; ct < wv * 12 + 12; ++ct) {   // 48 col-tiles over 4 waves
      const int cb = ct << 4;
      bf16x8 bw[8];
#pragma unroll
      for (int ks = 0; ks < 8; ++ks) {
        const int off = (cb + cl) * 256 + ks * 32 + g * 8;   // B[kk][c] = W[c][kk]
        if (PRE) {
          bw[ks] = *(const bf16x8*)(qkvWb + off);
        } else {
          float4 f0 = *(const float4*)(qkvWf + off);
          float4 f1 = *(const float4*)(qkvWf + off + 4);
          bw[ks] = pack8(f0, f1);
        }
      }
      f32x4 acc[4] = {Z, Z, Z, Z};
#pragma unroll
      for (int rt = 0; rt < 4; ++rt) {
        const int t = rt * 16 + cl;
        const unsigned short* xr = X + t * 256;
        const int t7 = t & 7;
#pragma unroll
        for (int ks = 0; ks < 8; ++ks) {
          bf16x8 a = *(const bf16x8*)(xr + (((ks * 4 + g) ^ t7) << 3));
          acc[rt] = MFMA16(a, bw[ks], acc[rt]);
        }
      }
      const int col = cb + cl;
      const float bias = qkvB[col];
      const int sel = col >> 8;            // 0=q 1=k 2=v
      const int hd_ = (col >> 5) & 7;      // head
      const int dim = col & 31;
#pragma unroll
      for (int rt = 0; rt < 4; ++rt) {
#pragma unroll
        for (int rg = 0; rg < 4; ++rg) {
          const int t = rt * 16 + g * 4 + rg;       // D row = token
          float v = acc[rt][rg] + bias;
          if (sel == 0) {
            sm[Q_OFF + hd_ * 2304 + t * 36 + dim] = f2bf(v * 0.17677669529663687f);
          } else if (sel == 1) {
            sm[K_OFF + hd_ * 2304 + t * 36 + dim] = f2bf(v);
          } else {
            sm[V_OFF + (hd_ * 32 + dim) * 72 + t] = f2bf(v);   // transposed
          }
        }
      }
    }
  }
  __syncthreads();

  // ---- attention: each wave owns 2 heads; swapped-operand QK^T and PV ----
  {
    const float* tab = (const float*)(sm + TAB_OFF);
    unsigned short* P = sm + P_OFF + wv * 4608;   // per-wave P scratch [64][72]
    float rsum[4];
#pragma unroll 1
    for (int hp = 0; hp < 2; ++hp) {
      const int h = wv * 2 + hp;
      const unsigned short* qh = sm + Q_OFF + h * 2304;
      const unsigned short* kh = sm + K_OFF + h * 2304;
      const unsigned short* vh = sm + V_OFF + h * (32 * 72);

      bf16x8 aq[4], ak[4];
#pragma unroll
      for (int qt = 0; qt < 4; ++qt) {
        aq[qt] = ld8u(qh + (qt * 16 + cl) * 36 + g * 8);
        ak[qt] = ld8u(kh + (qt * 16 + cl) * 36 + g * 8);
      }
      // s[qt][jt] = mfma(A=K rows, B=Q^T): D[row=k-token j][col=q-token i]
      f32x4 s[4][4];
#pragma unroll
      for (int qt = 0; qt < 4; ++qt)
#pragma unroll
        for (int jt = 0; jt < 4; ++jt)
          s[qt][jt] = MFMA16(ak[jt], aq[qt], Z);

      // bias + mask + row softmax (row i is lane-resident across g via shfl 16/32)
#pragma unroll
      for (int qt = 0; qt < 4; ++qt) {
        const int i = qt * 16 + cl;
        const int ri = i >> 3, ci = i & 7;
        const int ridi = (er ? ((ri < 4) ? 3 : 6) : 0) + (ec ? ((ci < 4) ? 1 : 2) : 0);
        float m = -1e30f;
#pragma unroll
        for (int jt = 0; jt < 4; ++jt) {
#pragma unroll
          for (int rg = 0; rg < 4; ++rg) {
            const int j = jt * 16 + g * 4 + rg;
            const int rj = j >> 3, cj = j & 7;
            const int ridj = (er ? ((rj < 4) ? 3 : 6) : 0) + (ec ? ((cj < 4) ? 1 : 2) : 0);
            float val = s[qt][jt][rg] + tab[((ri - rj + 7) * 15 + (ci - cj + 7)) * 8 + h];
            if (ridi != ridj) val -= 100.0f;
            s[qt][jt][rg] = val;
            m = fmaxf(m, val);
          }
        }
        m = fmaxf(m, __shfl_xor(m, 16));
        m = fmaxf(m, __shfl_xor(m, 32));
        float sum = 0.0f;
#pragma unroll
        for (int jt = 0; jt < 4; ++jt)
#pragma unroll
          for (int rg = 0; rg < 4; ++rg) {
            float e = __expf(s[qt][jt][rg] - m);
            s[qt][jt][rg] = e;
            sum += e;
          }
        sum += __shfl_xor(sum, 16);
        sum += __shfl_xor(sum, 32);
        rsum[qt] = 1.0f / sum;
      }

      // write unnormalized P (bf16) row-major [i][j]; regs give contiguous j -> b64 stores
#pragma unroll
      for (int qt = 0; qt < 4; ++qt) {
        const int i = qt * 16 + cl;
#pragma unroll
        for (int jt = 0; jt < 4; ++jt) {
          u16x4 pk;
          pk[0] = f2bf(s[qt][jt][0]); pk[1] = f2bf(s[qt][jt][1]);
          pk[2] = f2bf(s[qt][jt][2]); pk[3] = f2bf(s[qt][jt][3]);
          *(u16x4*)(P + i * 72 + jt * 16 + g * 4) = pk;
        }
      }

      // PV swapped: out^T[d][i] = sum_j v^T[d][j] P^T[j][i]
      f32x4 o[2][4] = {{Z, Z, Z, Z}, {Z, Z, Z, Z}};
#pragma unroll
      for (int ks = 0; ks < 2; ++ks) {
        bf16x8 av[2], bp[4];
        av[0] = *(const bf16x8*)(vh + cl * 72 + ks * 32 + g * 8);
        av[1] = *(const bf16x8*)(vh + (16 + cl) * 72 + ks * 32 + g * 8);
#pragma unroll
        for (int qt = 0; qt < 4; ++qt)
          bp[qt] = *(const bf16x8*)(P + (qt * 16 + cl) * 72 + ks * 32 + g * 8);
#pragma unroll
        for (int dt = 0; dt < 2; ++dt)
#pragma unroll
          for (int qt = 0; qt < 4; ++qt)
            o[dt][qt] = MFMA16(av[dt], bp[qt], o[dt][qt]);
      }
      // normalize + store attn_out (bf16) into this head's q region: [token][dim] stride 36
#pragma unroll
      for (int dt = 0; dt < 2; ++dt)
#pragma unroll
        for (int qt = 0; qt < 4; ++qt) {
          u16x4 pk;
#pragma unroll
          for (int rg = 0; rg < 4; ++rg) pk[rg] = f2bf(o[dt][qt][rg] * rsum[qt]);
          const int t = qt * 16 + cl;
          *(u16x4*)(sm + Q_OFF + h * 2304 + t * 36 + dt * 16 + g * 4) = pk;
        }
    }
  }
  __syncthreads();

  // ---- proj GEMM [64 x 256] @ Wp^T + bias, store fp32 with window-reverse + roll ----
  {
    for (int ct = wv * 4; ct < wv * 4 + 4; ++ct) {
      const int cb = ct << 4;
      bf16x8 bw[8];
#pragma unroll
      for (int ks = 0; ks < 8; ++ks) {
        const int off = (cb + cl) * 256 + ks * 32 + g * 8;
        if (PRE) {
          bw[ks] = *(const bf16x8*)(projWb + off);
        } else {
          float4 f0 = *(const float4*)(projWf + off);
          float4 f1 = *(const float4*)(projWf + off + 4);
          bw[ks] = pack8(f0, f1);
        }
      }
      f32x4 acc[4] = {Z, Z, Z, Z};
#pragma unroll
      for (int rt = 0; rt < 4; ++rt) {
#pragma unroll
        for (int ks = 0; ks < 8; ++ks) {   // k-chunk ks == head ks
          bf16x8 a = ld8u(sm + Q_OFF + ks * 2304 + (rt * 16 + cl) * 36 + g * 8);
          acc[rt] = MFMA16(a, bw[ks], acc[rt]);
        }
      }
      const int chn = cb + cl;
      const float pb = projB[chn];
#pragma unroll
      for (int rt = 0; rt < 4; ++rt) {
#pragma unroll
        for (int rg = 0; rg < 4; ++rg) {
          const int t = rt * 16 + g * 4 + rg;
          const int ho = (wi * 8 + (t >> 3) + 4) & 127;   // roll(+4) scatter
          const int wo = (wj * 8 + (t & 7) + 4) & 127;
          out[((size_t)((b << 14) + (ho << 7) + wo) << 8) + chn] = acc[rt][rg] + pb;
        }
      }
    }
  }
}

extern "C" void kernel_launch(void* const* d_in, const int* in_sizes, int n_in,
                              void* d_out, int out_size, void* d_ws, size_t ws_size,
                              hipStream_t stream) {
  const float* x     = (const float*)d_in[0];
  const float* qkvW  = (const float*)d_in[1];
  const float* qkvB  = (const float*)d_in[2];
  const float* projW = (const float*)d_in[3];
  const float* projB = (const float*)d_in[4];
  const float* tab   = (const float*)d_in[5];
  float* out = (float*)d_out;

  const size_t need = (size_t)(196608 + 65536) * sizeof(unsigned short);
  if (ws_size >= need) {
    unsigned short* wq = (unsigned short*)d_ws;
    unsigned short* wp = wq + 196608;
    conv_weights<<<dim3(768), dim3(256), 0, stream>>>(qkvW, projW, wq, wp);
    swin_fused<true><<<dim3(4096), dim3(256), 0, stream>>>(
        x, qkvW, qkvB, projW, projB, tab, wq, wp, out);
  } else {
    swin_fused<false><<<dim3(4096), dim3(256), 0, stream>>>(
        x, qkvW, qkvB, projW, projB, tab, nullptr, nullptr, out);
  }
}

// Round 11
// 817.359 us; speedup vs baseline: 1.2261x; 1.2261x over previous
//
#include <hip/hip_runtime.h>

// ---------------------------------------------------------------------------
// Swin shifted-window attention, fused, occupancy-optimized:
// one block = one 8x8 window, 4 waves, each wave owns 2 heads end-to-end.
// LDS 48KB -> 3 blocks/CU. bf16 MFMA 16x16x32, fp32 accumulate, fp32 in/out.
// ---------------------------------------------------------------------------

typedef float f32x4 __attribute__((ext_vector_type(4)));
typedef __bf16 bf16x8 __attribute__((ext_vector_type(8)));
typedef unsigned short u16x4 __attribute__((ext_vector_type(4)));
typedef unsigned short u16x8 __attribute__((ext_vector_type(8)));

#define MFMA16(a, b, c) __builtin_amdgcn_mfma_f32_16x16x32_bf16((a), (b), (c), 0, 0, 0)
#define QSCALE 0.17677669529663687f

__device__ __forceinline__ unsigned short f2bf(float f) {
  union { float f; unsigned u; } v; v.f = f;
  unsigned r = v.u + 0x7FFFu + ((v.u >> 16) & 1u);   // RNE
  return (unsigned short)(r >> 16);
}

__device__ __forceinline__ bf16x8 pack8(float4 f0, float4 f1) {
  union { u16x8 s; bf16x8 v; } u;
  u.s[0] = f2bf(f0.x); u.s[1] = f2bf(f0.y); u.s[2] = f2bf(f0.z); u.s[3] = f2bf(f0.w);
  u.s[4] = f2bf(f1.x); u.s[5] = f2bf(f1.y); u.s[6] = f2bf(f1.z); u.s[7] = f2bf(f1.w);
  return u.v;
}

// Pre-kernel: bf16 weights (q-rows pre-scaled) + masked rel-bias table
// ws layout: [0) wq bf16 196608][196608) wp bf16 65536][524288 B) bias_m f32 131072]
__global__ void prep(const float* __restrict__ qkvW, const float* __restrict__ projW,
                     const float* __restrict__ relTab,
                     unsigned short* __restrict__ wq, unsigned short* __restrict__ wp,
                     float* __restrict__ biasm) {
  int i = blockIdx.x * 256 + threadIdx.x;
  if (i < 196608) {
    float v = qkvW[i];
    if (i < 65536) v *= QSCALE;           // fold q-scale into Wq
    wq[i] = f2bf(v);
  }
  if (i < 65536) wp[i] = f2bf(projW[i]);
  if (i < 131072) {                        // bias_m[var][h][i][j]
    int j = i & 63, ii = (i >> 6) & 63, h = (i >> 12) & 7, var = i >> 15;
    int er = var >> 1, ec = var & 1;
    int ri = ii >> 3, ci = ii & 7, rj = j >> 3, cj = j & 7;
    int ridi = (er ? ((ri < 4) ? 3 : 6) : 0) + (ec ? ((ci < 4) ? 1 : 2) : 0);
    int ridj = (er ? ((rj < 4) ? 3 : 6) : 0) + (ec ? ((cj < 4) ? 1 : 2) : 0);
    float v = relTab[((ri - rj + 7) * 15 + (ci - cj + 7)) * 8 + h];
    if (ridi != ridj) v -= 100.0f;
    biasm[i] = v;
  }
}

// LDS (u16 units):
//  [0,16384)      x window chunk-XOR [32 ch-chunks][64 tok][8]; reused as attn_out
//  [16384,24576)  per-wave scratch 4 x 2048 (Q/K dim-chunked, V tok-chunked, P quarter)
//  [24576,28176)  (fallback only) rel-bias table 1800 f32
template <bool PRE>
__global__ __launch_bounds__(256, 3) void swin_fused(
    const float* __restrict__ x,
    const float* __restrict__ qkvWf, const float* __restrict__ qkvB,
    const float* __restrict__ projWf, const float* __restrict__ projB,
    const float* __restrict__ relTab,
    const unsigned short* __restrict__ qkvWb,
    const unsigned short* __restrict__ projWb,
    const float* __restrict__ biasm,
    float* __restrict__ out) {
  __shared__ unsigned short sm[PRE ? 24576 : 28192];
  const f32x4 Z = {0.0f, 0.0f, 0.0f, 0.0f};

  const int tid = threadIdx.x;
  const int wv = tid >> 6, lane = tid & 63, g = lane >> 4, cl = lane & 15;
  const int blk = blockIdx.x, b = blk >> 8, w = blk & 255, wi = w >> 4, wj = w & 15;
  const bool er = (wi == 15), ec = (wj == 15);
  const int var = (er ? 2 : 0) + (ec ? 1 : 0);

  if (!PRE) {
    float* t = (float*)(sm + 24576);
    for (int i = tid; i < 1800; i += 256) t[i] = relTab[i];
  }

  // ---- stage x: shift-gather fp32->bf16 into chunk-XOR layout ----
  {
    const float* xb = x + (size_t)b * (128 * 128 * 256);
#pragma unroll
    for (int it = 0; it < 8; ++it) {
      int idx = tid + it * 256, t = idx >> 5, ch = idx & 31;
      int hh = (wi * 8 + (t >> 3) + 4) & 127;
      int ww = (wj * 8 + (t & 7) + 4) & 127;
      const float* src = xb + ((((hh << 7) + ww) << 8) + ch * 8);
      float4 f0 = *(const float4*)src;
      float4 f1 = *(const float4*)(src + 4);
      union { u16x8 s; bf16x8 v; } pk;
      pk.s[0] = f2bf(f0.x); pk.s[1] = f2bf(f0.y); pk.s[2] = f2bf(f0.z); pk.s[3] = f2bf(f0.w);
      pk.s[4] = f2bf(f1.x); pk.s[5] = f2bf(f1.y); pk.s[6] = f2bf(f1.z); pk.s[7] = f2bf(f1.w);
      *(u16x8*)(sm + ch * 512 + ((t ^ (2 * (ch & 3))) << 3)) = pk.s;
    }
  }
  __syncthreads();

  unsigned short* scr = sm + 16384 + wv * 2048;
  const int hA = wv * 2, hB = hA + 1;

  // x / attn_out read: row=token, c=channel-chunk -> one b128
  auto ldx = [&](int row, int c) -> bf16x8 {
    return *(const bf16x8*)(sm + c * 512 + ((row ^ (2 * (c & 3))) << 3));
  };
  // [64x256]@[256x32] GEMM -> acc[ct 0..1][rt 0..3]
  auto gemm32 = [&](int colbase, f32x4 (&acc)[2][4]) {
#pragma unroll
    for (int ct = 0; ct < 2; ++ct) {
      const int col = colbase + ct * 16 + cl;
      bf16x8 bw[8];
#pragma unroll
      for (int ks = 0; ks < 8; ++ks) {
        const int off = col * 256 + ks * 32 + g * 8;
        if (PRE) bw[ks] = *(const bf16x8*)(qkvWb + off);
        else {
          float4 a = *(const float4*)(qkvWf + off);
          float4 c2 = *(const float4*)(qkvWf + off + 4);
          bw[ks] = pack8(a, c2);
        }
      }
#pragma unroll
      for (int rt = 0; rt < 4; ++rt) {
        acc[ct][rt] = Z;
#pragma unroll
        for (int ks = 0; ks < 8; ++ks)
          acc[ct][rt] = MFMA16(ldx(rt * 16 + cl, ks * 4 + g), bw[ks], acc[ct][rt]);
      }
    }
  };
  // Q/K epilogue -> scratch dim-chunked [cQ=dim>>3][tok ^ 2(cQ&3)][dim&7]
  auto epiQK = [&](f32x4 (&acc)[2][4], int colbase, bool isQ) {
#pragma unroll
    for (int ct = 0; ct < 2; ++ct) {
      const int col = colbase + ct * 16 + cl;
      float bs = qkvB[col]; if (isQ) bs *= QSCALE;
      const int cQ = 2 * ct + (cl >> 3), Xr = 2 * (cQ & 3);
#pragma unroll
      for (int rt = 0; rt < 4; ++rt)
#pragma unroll
        for (int r = 0; r < 4; ++r) {
          float v = acc[ct][rt][r];
          if (!PRE && isQ) v *= QSCALE;
          scr[cQ * 512 + (((rt * 16 + 4 * g + r) ^ Xr) << 3) + (cl & 7)] = f2bf(v + bs);
        }
    }
  };
  auto ldQK = [&](int it) -> bf16x8 {   // A/B frag: row=it*16+cl, dims 8g..8g+7
    return *(const bf16x8*)(scr + g * 512 + (((it * 16 + cl) ^ (2 * g)) << 3));
  };
  // V epilogue -> scratch tok-chunked [cV=tok>>3][dim ^ 2(cV&3)][tok&7] (u16x4 packs)
  auto epiV = [&](f32x4 (&acc)[2][4], int colbase) {
#pragma unroll
    for (int ct = 0; ct < 2; ++ct) {
      const int col = colbase + ct * 16 + cl;
      const float bs = qkvB[col];
#pragma unroll
      for (int rt = 0; rt < 4; ++rt) {
        const int cV = 2 * rt + (g >> 1);
        const int pos = (ct * 16 + cl) ^ (2 * (cV & 3));
        u16x4 pk;
#pragma unroll
        for (int r = 0; r < 4; ++r) pk[r] = f2bf(acc[ct][rt][r] + bs);
        *(u16x4*)(scr + cV * 256 + pos * 8 + 4 * (g & 1)) = pk;
      }
    }
  };
  auto ldV = [&](int ks, int dt) -> bf16x8 {  // B frag: k=tok 32ks+8g.., col=dim 16dt+cl
    const int c = ks * 4 + g;
    return *(const bf16x8*)(scr + c * 256 + (((dt * 16 + cl) ^ (2 * (c & 3))) << 3));
  };
  // attention for one head: swapped QK^T, quarter-wise softmax, P via scratch, PV
  auto attnHead = [&](int h, bf16x8 (&aq)[4], bf16x8 (&ak)[4], bf16x8 (&bv)[2][2],
                      f32x4 (&o)[4][2]) {
    bf16x8 ap[4][2];
#pragma unroll
    for (int qt = 0; qt < 4; ++qt) {
      f32x4 s4[4];
#pragma unroll
      for (int jt = 0; jt < 4; ++jt) s4[jt] = MFMA16(ak[jt], aq[qt], Z);
      const int i = qt * 16 + cl;
      if (PRE) {
        const float* bp = biasm + (((var * 8 + h) * 64 + i) << 6) + g * 4;
#pragma unroll
        for (int jt = 0; jt < 4; ++jt) s4[jt] += *(const f32x4*)(bp + jt * 16);
      } else {
        const float* tab = (const float*)(sm + 24576);
        const int ri = i >> 3, ci = i & 7;
        const int ridi = (er ? ((ri < 4) ? 3 : 6) : 0) + (ec ? ((ci < 4) ? 1 : 2) : 0);
#pragma unroll
        for (int jt = 0; jt < 4; ++jt)
#pragma unroll
          for (int r = 0; r < 4; ++r) {
            const int j = jt * 16 + 4 * g + r, rj = j >> 3, cj = j & 7;
            const int ridj = (er ? ((rj < 4) ? 3 : 6) : 0) + (ec ? ((cj < 4) ? 1 : 2) : 0);
            float v2 = s4[jt][r] + tab[((ri - rj + 7) * 15 + (ci - cj + 7)) * 8 + h];
            if (ridi != ridj) v2 -= 100.0f;
            s4[jt][r] = v2;
          }
      }
      float mx = -1e30f;
#pragma unroll
      for (int jt = 0; jt < 4; ++jt)
#pragma unroll
        for (int r = 0; r < 4; ++r) mx = fmaxf(mx, s4[jt][r]);
      mx = fmaxf(mx, __shfl_xor(mx, 16));
      mx = fmaxf(mx, __shfl_xor(mx, 32));
      float sum = 0.0f;
#pragma unroll
      for (int jt = 0; jt < 4; ++jt)
#pragma unroll
        for (int r = 0; r < 4; ++r) {
          float e = __expf(s4[jt][r] - mx);
          s4[jt][r] = e; sum += e;
        }
      sum += __shfl_xor(sum, 16);
      sum += __shfl_xor(sum, 32);
      const float rs = 1.0f / sum;
      // P quarter -> scratch [cP=j>>3][row(i&15) ^ 2(cP&3)][j&7]
#pragma unroll
      for (int jt = 0; jt < 4; ++jt) {
        const int cP = 2 * jt + (g >> 1);
        const int pos = cl ^ (2 * (cP & 3));
        u16x4 pk;
#pragma unroll
        for (int r = 0; r < 4; ++r) pk[r] = f2bf(s4[jt][r] * rs);
        *(u16x4*)(scr + cP * 128 + pos * 8 + 4 * (g & 1)) = pk;
      }
#pragma unroll
      for (int ks = 0; ks < 2; ++ks)
        ap[qt][ks] = *(const bf16x8*)(scr + (ks * 4 + g) * 128 + ((cl ^ (2 * g)) << 3));
    }
#pragma unroll
    for (int it = 0; it < 4; ++it)
#pragma unroll
      for (int dt = 0; dt < 2; ++dt) {
        o[it][dt] = Z;
#pragma unroll
        for (int ks = 0; ks < 2; ++ks)
          o[it][dt] = MFMA16(ap[it][ks], bv[ks][dt], o[it][dt]);
      }
  };
  auto writeO = [&](int h, f32x4 (&o)[4][2]) {
#pragma unroll
    for (int it = 0; it < 4; ++it)
#pragma unroll
      for (int dt = 0; dt < 2; ++dt) {
        const int d = h * 32 + dt * 16 + cl;
        const int cA = d >> 3, Xr = 2 * (cA & 3);
#pragma unroll
        for (int r = 0; r < 4; ++r)
          sm[cA * 512 + (((it * 16 + 4 * g + r) ^ Xr) << 3) + (d & 7)] = f2bf(o[it][dt][r]);
      }
  };

  // ---- per-wave QKV (heads A,B), head-A attention overlapped before VB ----
  bf16x8 aqA[4], akA[4], bvA[2][2], aqB[4], akB[4], bvB[2][2];
  {
    f32x4 acc[2][4];
    gemm32(hA * 32, acc);        epiQK(acc, hA * 32, true);
#pragma unroll
    for (int i2 = 0; i2 < 4; ++i2) aqA[i2] = ldQK(i2);
    gemm32(256 + hA * 32, acc);  epiQK(acc, 256 + hA * 32, false);
#pragma unroll
    for (int i2 = 0; i2 < 4; ++i2) akA[i2] = ldQK(i2);
    gemm32(512 + hA * 32, acc);  epiV(acc, 512 + hA * 32);
#pragma unroll
    for (int ks = 0; ks < 2; ++ks)
#pragma unroll
      for (int dt = 0; dt < 2; ++dt) bvA[ks][dt] = ldV(ks, dt);
    gemm32(hB * 32, acc);        epiQK(acc, hB * 32, true);
#pragma unroll
    for (int i2 = 0; i2 < 4; ++i2) aqB[i2] = ldQK(i2);
    gemm32(256 + hB * 32, acc);  epiQK(acc, 256 + hB * 32, false);
#pragma unroll
    for (int i2 = 0; i2 < 4; ++i2) akB[i2] = ldQK(i2);
  }
  f32x4 oA[4][2];
  attnHead(hA, aqA, akA, bvA, oA);       // uses scr for P; x still intact
  {
    f32x4 acc[2][4];
    gemm32(512 + hB * 32, acc);  epiV(acc, 512 + hB * 32);
#pragma unroll
    for (int ks = 0; ks < 2; ++ks)
#pragma unroll
      for (int dt = 0; dt < 2; ++dt) bvB[ks][dt] = ldV(ks, dt);
  }
  __syncthreads();                        // all x reads done -> region becomes attn_out
  writeO(hA, oA);
  {
    f32x4 oB[4][2];
    attnHead(hB, aqB, akB, bvB, oB);
    writeO(hB, oB);
  }
  __syncthreads();

  // ---- proj GEMM [64x256]@[256x256] + bias, fp32 store with reverse+roll ----
#pragma unroll 1
  for (int ct = wv * 4; ct < wv * 4 + 4; ++ct) {
    const int col = ct * 16 + cl;
    bf16x8 bw[8];
#pragma unroll
    for (int ks = 0; ks < 8; ++ks) {
      const int off = col * 256 + ks * 32 + g * 8;
      if (PRE) bw[ks] = *(const bf16x8*)(projWb + off);
      else {
        float4 a = *(const float4*)(projWf + off);
        float4 c2 = *(const float4*)(projWf + off + 4);
        bw[ks] = pack8(a, c2);
      }
    }
    f32x4 acc[4];
#pragma unroll
    for (int rt = 0; rt < 4; ++rt) {
      acc[rt] = Z;
#pragma unroll
      for (int ks = 0; ks < 8; ++ks)
        acc[rt] = MFMA16(ldx(rt * 16 + cl, ks * 4 + g), bw[ks], acc[rt]);
    }
    const float pb = projB[col];
#pragma unroll
    for (int rt = 0; rt < 4; ++rt)
#pragma unroll
      for (int r = 0; r < 4; ++r) {
        const int t = rt * 16 + 4 * g + r;
        const int ho = (wi * 8 + (t >> 3) + 4) & 127;
        const int wo = (wj * 8 + (t & 7) + 4) & 127;
        out[((size_t)((b << 14) + (ho << 7) + wo) << 8) + col] = acc[rt][r] + pb;
      }
  }
}

extern "C" void kernel_launch(void* const* d_in, const int* in_sizes, int n_in,
                              void* d_out, int out_size, void* d_ws, size_t ws_size,
                              hipStream_t stream) {
  const float* x     = (const float*)d_in[0];
  const float* qkvW  = (const float*)d_in[1];
  const float* qkvB  = (const float*)d_in[2];
  const float* projW = (const float*)d_in[3];
  const float* projB = (const float*)d_in[4];
  const float* tab   = (const float*)d_in[5];
  float* out = (float*)d_out;

  const size_t needW = (size_t)(196608 + 65536) * sizeof(unsigned short);   // 524288
  const size_t need  = needW + (size_t)131072 * sizeof(float);              // 1 MiB
  if (ws_size >= need) {
    unsigned short* wq = (unsigned short*)d_ws;
    unsigned short* wp = wq + 196608;
    float* biasm = (float*)((char*)d_ws + needW);
    prep<<<dim3(768), dim3(256), 0, stream>>>(qkvW, projW, tab, wq, wp, biasm);
    swin_fused<true><<<dim3(4096), dim3(256), 0, stream>>>(
        x, qkvW, qkvB, projW, projB, tab, wq, wp, biasm, out);
  } else {
    swin_fused<false><<<dim3(4096), dim3(256), 0, stream>>>(
        x, qkvW, qkvB, projW, projB, tab, nullptr, nullptr, nullptr, out);
  }
}